// Round 16
// baseline (540.666 us; speedup 1.0000x reference)
//
#include <hip/hip_runtime.h>

#define ND   2048
#define BB   16384

typedef unsigned short u16;
typedef unsigned int u32;
typedef unsigned long long u64;
typedef __attribute__((ext_vector_type(8))) short short8;
typedef __attribute__((ext_vector_type(4))) float f32x4;

__device__ inline float bf2f(u16 u) {
    union { u32 i; float f; } v; v.i = ((u32)u) << 16; return v.f;
}
__device__ inline u16 f2bf(float f) {
    union { float f; u32 i; } v; v.f = f;
    u32 i = v.i + 0x7fffu + ((v.i >> 16) & 1u);
    return (u16)(i >> 16);
}
__device__ inline float seluf(float x) {
    const float sc = 1.0507009873554805f, al = 1.6732632423543772f;
    return x > 0.f ? sc * x : sc * al * expm1f(x);
}

// ---- inline wave-level dtype sniffer: true => inputs are float32 ----------
__device__ inline bool detect_f32(const u16* demb) {
    int lane = threadIdx.x & 63;
    int sane = 0;
    #pragma unroll
    for (int i = 0; i < 2; i++) {
        u16 u = demb[lane * 4 + i * 2];   // even u16 idx = f32 low halves
        int e = (u >> 7) & 0xFF;
        if (u == 0 || (e >= 0x66 && e <= 0x8C)) sane++;
    }
    #pragma unroll
    for (int o = 32; o > 0; o >>= 1) sane += __shfl_down(sane, o, 64);
    return __shfl(sane, 0, 64) < 75;      // bf16 ~126/128 sane; f32 ~20/128
}
__device__ inline float rdv(const void* p, size_t i, bool f32) {
    return f32 ? ((const float*)p)[i] : bf2f(((const u16*)p)[i]);
}

// =================== PREP (one launch, flat grid ranges) ====================
// [0,4096)    : e_p -> epT bf16 transpose (32x32 tiles)
// [4096,5120) : koqs (8 rows x 1 mat per block)
// [5120,5216) : six 128x128 weight transposes (16 tiles each)
// [5216,5218) : embedding column sums
// [5218]      : combined biases + zero loss acc/counter
struct PREP {
    const void* e_p; u16* epT;
    const void* demb; const void* pemb;
    const void* Wa1d; const void* ba1d; const void* Wa1p; const void* ba1p;
    float* ko_d; float* qs_d; float* ko_p; float* qs_p;
    const void* w1; const void* w2; const void* wdg; const void* wd2;
    const void* wpg; const void* wp3;
    u16* W1T; u16* W2T; u16* WcTe; u16* WcTp;
    float* esum_d; float* esum_p;
    const void* bdg_lin; const void* bdg; const void* bd2;
    const void* bpg_lin; const void* bpg; const void* bp3;
    u16* b_e; u16* b_p;
    float* acc; u32* cnt;
};

__global__ __launch_bounds__(256) void prep(PREP p) {
    bool f32 = detect_f32((const u16*)p.demb);
    int b = blockIdx.x;
    int tid = threadIdx.x;
    if (b < 4096) {                       // ---- epT transpose ----
        __shared__ u16 tile[32][33];
        int c0 = (b & 63) * 32, r0 = (b >> 6) * 32;
        int x = tid & 31, y = tid >> 5;   // y 0..7
        for (int i = y; i < 32; i += 8)
            tile[i][x] = f32 ? f2bf(((const float*)p.e_p)[(size_t)(r0 + i) * 2048 + c0 + x])
                             : ((const u16*)p.e_p)[(size_t)(r0 + i) * 2048 + c0 + x];
        __syncthreads();
        int rr = r0 + x;
        for (int i = y; i < 32; i += 8)
            p.epT[(size_t)(c0 + i) * 2048 + rr] = tile[x][i];
    } else if (b < 5120) {                // ---- koqs ----
        __shared__ float Wl[4096];
        __shared__ float xl[8][128];
        int kb = b - 4096;
        int mat = kb & 3, row0 = (kb >> 2) * 8;
        const void* emb; const void* W; size_t woff; const void* bias; float* out;
        switch (mat) {
            case 0:  emb = p.pemb; W = p.Wa1d; woff = 0;    bias = nullptr; out = p.ko_d; break;
            case 1:  emb = p.demb; W = p.Wa1d; woff = 4096; bias = p.ba1d;  out = p.qs_d; break;
            case 2:  emb = p.demb; W = p.Wa1p; woff = 0;    bias = nullptr; out = p.ko_p; break;
            default: emb = p.pemb; W = p.Wa1p; woff = 4096; bias = p.ba1p;  out = p.qs_p; break;
        }
        for (int i = tid; i < 4096; i += 256) Wl[i] = rdv(W, woff + i, f32);
        for (int i = tid; i < 1024; i += 256) {
            int r = i >> 7, k = i & 127;
            xl[r][k] = rdv(emb, (size_t)(row0 + r) * 128 + k, f32);
        }
        __syncthreads();
        int r = tid >> 5, a = tid & 31;
        float s = 0.f;
        #pragma unroll 8
        for (int k = 0; k < 128; k++) s += xl[r][k] * Wl[k * 32 + a];
        if (bias) s += rdv(bias, a, f32);
        out[(size_t)(row0 + r) * 32 + a] = s;
    } else if (b < 5216) {                // ---- small W transposes ----
        __shared__ u16 tile[32][33];
        int sb = b - 5120;
        int z = sb >> 4, t16 = sb & 15;
        int c0 = (t16 & 3) * 32, r0 = (t16 >> 2) * 32;
        const void* in; u16* out; int ldo, ooff;
        switch (z) {
            case 0:  in = p.w1;  out = p.W1T;  ldo = 128; ooff = 0;   break;
            case 1:  in = p.w2;  out = p.W2T;  ldo = 128; ooff = 0;   break;
            case 2:  in = p.wdg; out = p.WcTe; ldo = 256; ooff = 0;   break;
            case 3:  in = p.wd2; out = p.WcTe; ldo = 256; ooff = 128; break;
            case 4:  in = p.wpg; out = p.WcTp; ldo = 256; ooff = 0;   break;
            default: in = p.wp3; out = p.WcTp; ldo = 256; ooff = 128; break;
        }
        int x = tid & 31, y = tid >> 5;
        for (int i = y; i < 32; i += 8)
            tile[i][x] = f2bf(rdv(in, (size_t)(r0 + i) * 128 + c0 + x, f32));
        __syncthreads();
        int rr = r0 + x;
        for (int i = y; i < 32; i += 8)
            out[(size_t)(c0 + i) * ldo + ooff + rr] = tile[x][i];
    } else if (b < 5218) {                // ---- embsum ----
        __shared__ float part[2][128];
        const void* emb = (b == 5217) ? p.pemb : p.demb;
        float* dst = (b == 5217) ? p.esum_p : p.esum_d;
        int d = tid & 127, h = tid >> 7;
        float s = 0.f;
        for (int r = h; r < 2048; r += 2)
            s += rdv(emb, (size_t)r * 128 + d, f32);
        part[h][d] = s;
        __syncthreads();
        if (tid < 128) dst[tid] = part[0][tid] + part[1][tid];
    } else {                              // ---- biases + zero acc ----
        if (tid < 128) {
            p.b_e[tid] = f2bf(rdv(p.bdg_lin, tid, f32) + rdv(p.bdg, tid, f32) +
                              rdv(p.bd2, tid, f32));
            p.b_p[tid] = f2bf(rdv(p.bpg_lin, tid, f32) + rdv(p.bpg, tid, f32) +
                              rdv(p.bp3, tid, f32));
        }
        if (tid == 254) *p.acc = 0.f;
        if (tid == 255) *p.cnt = 0u;
    }
}

// =================== sparse fused aggregation v3 ===========================
// Phase 1: ballot-compact edges (no score). Phase 2: DENSE score compute over
// compacted list (full lane utilization). Then wave-0 wsum + accumulation.
#define ECAP 512
struct SG {
    const void* adj[4]; int adjbf[4];
    const float* qs[4]; const float* ko[4];
    const void* w2[4]; const void* b2[4];
    const float* embsum[4];
    const void* emb[4];
    u16* outp[4]; int coff[4];
    int mode[4];
    const void* demb;
};

__global__ __launch_bounds__(512, 4) void sagg3(SG p) {
    __shared__ float accQ[4][128];
    __shared__ float qsh[32], w2sh[32];
    __shared__ float wlist[ECAP];
    __shared__ int jlist[ECAP];
    __shared__ int ecnt;
    __shared__ float wsum_sh;
    bool f32 = detect_f32((const u16*)p.demb);
    int z = blockIdx.y;
    int row = blockIdx.x;
    int tid = threadIdx.x;
    int lane = tid & 63;
    int mode = p.mode[z];
    bool f32a = (p.adjbf[z] == 0) && f32;
    if (tid < 128) { accQ[0][tid] = 0.f; accQ[1][tid] = 0.f;
                     accQ[2][tid] = 0.f; accQ[3][tid] = 0.f; }
    if (tid == 0) ecnt = 0;
    if (mode == 0) {
        if (tid < 32) qsh[tid] = p.qs[z][(size_t)row * 32 + tid];
        else if (tid < 64) w2sh[tid - 32] = (float)rdv(p.w2[z], tid - 32, f32);
    }
    __syncthreads();
    // phase 1: scan + compact (no score)
    float av[4];
    #pragma unroll
    for (int c = 0; c < 4; c++)
        av[c] = f32a ? ((const float*)p.adj[z])[(size_t)row * 2048 + c * 512 + tid]
                     : bf2f(((const u16*)p.adj[z])[(size_t)row * 2048 + c * 512 + tid]);
    u64 ltmask = ((u64)1 << lane) - 1;
    #pragma unroll
    for (int c = 0; c < 4; c++) {
        bool has = av[c] != 0.f;
        u64 mask = __ballot(has);
        int cnt = __popcll(mask);
        int base0 = 0;
        if (lane == 0 && cnt) base0 = atomicAdd(&ecnt, cnt);
        int base = __shfl(base0, 0, 64);
        int pos = base + (int)__popcll(mask & ltmask);
        if (has && pos < ECAP) { jlist[pos] = c * 512 + tid; wlist[pos] = av[c]; }
    }
    __syncthreads();
    int E = min(ecnt, ECAP);
    // phase 2: dense score compute over compacted edges (attention only)
    if (mode == 0) {
        float b2v = (float)rdv(p.b2[z], 0, f32);
        const float* ko = p.ko[z];
        for (int e = tid; e < E; e += 512) {
            int j = jlist[e];
            const float4* kp = (const float4*)(ko + (size_t)j * 32);
            float s = 0.f;
            #pragma unroll
            for (int qd = 0; qd < 8; qd++) {
                float4 kv = kp[qd];
                s += fmaxf(qsh[qd * 4 + 0] + kv.x, 0.f) * w2sh[qd * 4 + 0];
                s += fmaxf(qsh[qd * 4 + 1] + kv.y, 0.f) * w2sh[qd * 4 + 1];
                s += fmaxf(qsh[qd * 4 + 2] + kv.z, 0.f) * w2sh[qd * 4 + 2];
                s += fmaxf(qsh[qd * 4 + 3] + kv.w, 0.f) * w2sh[qd * 4 + 3];
            }
            s = fmaxf(s + b2v, 0.f);
            wlist[e] = expm1f(s);
        }
        __syncthreads();
    }
    // wave-0 weight-sum
    if (tid < 64) {
        float s = 0.f;
        for (int i = lane; i < E; i += 64) s += wlist[i];
        #pragma unroll
        for (int o = 32; o > 0; o >>= 1) s += __shfl_down(s, o, 64);
        if (lane == 0) wsum_sh = s;
    }
    // edge accumulation: 4-way edge parallel, 4-deep unroll
    int d = tid & 127, q = tid >> 7;
    const void* emb = p.emb[z];
    float acc = 0.f;
    int e = q;
    for (; e + 12 < E; e += 16) {
        float w0 = wlist[e],     w1 = wlist[e + 4];
        float w2 = wlist[e + 8], w3 = wlist[e + 12];
        int j0 = jlist[e],       j1 = jlist[e + 4];
        int j2 = jlist[e + 8],   j3 = jlist[e + 12];
        float v0 = rdv(emb, (size_t)j0 * 128 + d, f32);
        float v1 = rdv(emb, (size_t)j1 * 128 + d, f32);
        float v2 = rdv(emb, (size_t)j2 * 128 + d, f32);
        float v3 = rdv(emb, (size_t)j3 * 128 + d, f32);
        acc += w0 * v0 + w1 * v1 + w2 * v2 + w3 * v3;
    }
    for (; e < E; e += 4)
        acc += wlist[e] * rdv(emb, (size_t)jlist[e] * 128 + d, f32);
    accQ[q][d] = acc;
    __syncthreads();
    if (tid < 128) {
        float v = accQ[0][tid] + accQ[1][tid] + accQ[2][tid] + accQ[3][tid];
        float denom;
        if (mode == 0) { v += p.embsum[z][tid]; denom = 2048.f + wsum_sh; }
        else denom = wsum_sh + 1e-8f;
        p.outp[z][(size_t)row * 256 + p.coff[z] + tid] = f2bf(v / denom);
    }
}

// =================== LDS-tiled MFMA GEMM (2-desc, optional gather-A) ========
struct GD2 {
    const u16* A[2]; const u16* BT[2]; u16* C[2];
    const void* bias[2]; int braw[2];
    int lda[2], ldb[2], ldc[2], coff[2], kiters[2], act[2], gather[2];
    const u16 *he, *hp; const int *di, *dr;
    const void* demb;
};

#define PADK 136

__global__ __launch_bounds__(256, 2) void gemmF(GD2 g) {
    __shared__ __align__(16) u16 As[16][PADK];
    __shared__ __align__(16) u16 Bs[128][PADK];
    bool f32 = detect_f32((const u16*)g.demb);
    int z = blockIdx.y;
    const u16* A = g.A[z];
    const u16* BT = g.BT[z];
    int lda = g.lda[z], ldb = g.ldb[z];
    int kiters = g.kiters[z];
    int gath = g.gather[z];
    int tid = threadIdx.x;
    int lane = tid & 63, wv = tid >> 6;
    int mrow = lane & 15, quad = lane >> 4;
    int m0 = blockIdx.x * 16;
    int c0 = wv * 32;
    int sr = tid >> 4, sk = (tid & 15) * 8;
    f32x4 acc0 = {0.f, 0.f, 0.f, 0.f}, acc1 = {0.f, 0.f, 0.f, 0.f};

    short8 ra, rb[8];
    auto ldstage = [&](int kb) {
        if (gath) {
            int r = m0 + sr;
            int ia = g.di[r], ic = g.dr[r];
            short8 he8 = *(const short8*)(g.he + (size_t)ia * 128 + sk);
            short8 hp8 = *(const short8*)(g.hp + (size_t)ic * 128 + sk);
            #pragma unroll
            for (int i = 0; i < 8; i++)
                ra[i] = (short)f2bf(bf2f((u16)he8[i]) * bf2f((u16)hp8[i]));
        } else {
            ra = *(const short8*)(A + (size_t)(m0 + sr) * lda + kb + sk);
        }
        const u16* bbase = BT + (size_t)sr * ldb + kb + sk;
        #pragma unroll
        for (int i = 0; i < 8; i++)
            rb[i] = *(const short8*)(bbase + (size_t)i * 16 * ldb);
    };
    auto ststage = [&]() {
        *(short8*)(&As[sr][sk]) = ra;
        #pragma unroll
        for (int i = 0; i < 8; i++)
            *(short8*)(&Bs[i * 16 + sr][sk]) = rb[i];
    };
    auto compute = [&]() {
        #pragma unroll
        for (int ks = 0; ks < 4; ks++) {
            short8 af = *(const short8*)(&As[mrow][ks * 32 + quad * 8]);
            short8 b0 = *(const short8*)(&Bs[c0 + mrow][ks * 32 + quad * 8]);
            short8 b1 = *(const short8*)(&Bs[c0 + 16 + mrow][ks * 32 + quad * 8]);
            acc0 = __builtin_amdgcn_mfma_f32_16x16x32_bf16(af, b0, acc0, 0, 0, 0);
            acc1 = __builtin_amdgcn_mfma_f32_16x16x32_bf16(af, b1, acc1, 0, 0, 0);
        }
    };

    ldstage(0);
    #pragma unroll 1
    for (int it = 0; it < kiters - 1; ++it) {
        ststage();
        __syncthreads();
        ldstage((it + 1) * 128);
        compute();
        __syncthreads();
    }
    ststage();
    __syncthreads();
    compute();

    const void* bi = g.bias[z];
    bool braw = g.braw[z] != 0;
    u16* C = g.C[z];
    int ldc = g.ldc[z], coff = g.coff[z], act = g.act[z];
    int n0 = c0 + mrow, n1 = n0 + 16;
    float bv0, bv1;
    if (braw) { bv0 = rdv(bi, n0, f32); bv1 = rdv(bi, n1, f32); }
    else      { bv0 = bf2f(((const u16*)bi)[n0]); bv1 = bf2f(((const u16*)bi)[n1]); }
    #pragma unroll
    for (int r = 0; r < 4; r++) {
        int rw = m0 + quad * 4 + r;
        float v0 = acc0[r] + bv0, v1 = acc1[r] + bv1;
        if (act) { v0 = seluf(v0); v1 = seluf(v1); }
        C[(size_t)rw * ldc + coff + n0] = f2bf(v0);
        C[(size_t)rw * ldc + coff + n1] = f2bf(v1);
    }
}

// =================== z / sigmoid / loss (self-finalizing) ===================
__global__ __launch_bounds__(256) void zloss2(
    const u16* __restrict__ X2, const void* __restrict__ wpred,
    const void* __restrict__ bpred, const int* __restrict__ labels,
    float* __restrict__ out, float* __restrict__ acc, u32* __restrict__ cnt,
    const void* __restrict__ demb) {
    __shared__ float wp[128];
    __shared__ float ls[256];
    bool f32 = detect_f32((const u16*)demb);
    int tid = threadIdx.x;
    if (tid < 128) wp[tid] = rdv(wpred, tid, f32);
    __syncthreads();
    int b = blockIdx.x * 256 + tid;
    const uint4* xp = (const uint4*)(X2 + (size_t)b * 128);
    float z = 0.f;
    #pragma unroll
    for (int i = 0; i < 16; i++) {
        uint4 q = xp[i];
        u32 u[4] = {q.x, q.y, q.z, q.w};
        #pragma unroll
        for (int c = 0; c < 4; c++) {
            z += bf2f((u16)(u[c] & 0xffff)) * wp[i * 8 + c * 2];
            z += bf2f((u16)(u[c] >> 16)) * wp[i * 8 + c * 2 + 1];
        }
    }
    z += rdv(bpred, 0, f32);
    out[1 + b] = 1.f / (1.f + __expf(-z));
    float y = (float)labels[b];
    ls[tid] = fmaxf(z, 0.f) - z * y + log1pf(__expf(-fabsf(z)));
    __syncthreads();
    for (int o = 128; o > 0; o >>= 1) {
        if (tid < o) ls[tid] += ls[tid + o];
        __syncthreads();
    }
    if (tid == 0) {
        atomicAdd(acc, ls[0]);
        __threadfence();
        u32 t = atomicAdd(cnt, 1u);
        if (t == 63) {
            __threadfence();
            out[0] = *(volatile float*)acc * (1.f / 16384.f);
        }
    }
}

// =================== launch (6 dispatches) ==================================
extern "C" void kernel_launch(void* const* d_in, const int* in_sizes, int n_in,
                              void* d_out, int out_size, void* d_ws, size_t ws_size,
                              hipStream_t stream) {
    const void* e_p_adj = d_in[0];
    const void* e_e_adj = d_in[1];
    const void* p_p_adj = d_in[2];
    const int* in_dis  = (const int*)d_in[3];
    const int* in_drug = (const int*)d_in[4];
    const int* labels  = (const int*)d_in[5];
    const void* demb = d_in[6];
    const void* pemb = d_in[7];
    float* out = (float*)d_out;

    // -------- workspace (~17 MB) --------
    char* ws = (char*)d_ws;
    size_t off = 0;
    auto take = [&](size_t bytes) { char* p = ws + off; off = (off + bytes + 255) & ~(size_t)255; return p; };
    u16*   epT   = (u16*)take((size_t)2048 * 2048 * 2);   // 8 MB; X2 aliases later
    u16*   X1    = (u16*)take((size_t)BB * 128 * 2);      // 4 MB
    float* ko_d  = (float*)take((size_t)2048 * 32 * 4);
    float* qs_d  = (float*)take((size_t)2048 * 32 * 4);
    float* ko_p  = (float*)take((size_t)2048 * 32 * 4);
    float* qs_p  = (float*)take((size_t)2048 * 32 * 4);
    u16*   A_e   = (u16*)take((size_t)2048 * 256 * 2);
    u16*   A_p   = (u16*)take((size_t)2048 * 256 * 2);
    u16*   WcTe  = (u16*)take((size_t)128 * 256 * 2);
    u16*   WcTp  = (u16*)take((size_t)128 * 256 * 2);
    u16*   W1T   = (u16*)take((size_t)128 * 128 * 2);
    u16*   W2T   = (u16*)take((size_t)128 * 128 * 2);
    u16*   b_e   = (u16*)take(256);
    u16*   b_p   = (u16*)take(256);
    u16*   h_e   = (u16*)take((size_t)2048 * 128 * 2);
    u16*   h_p   = (u16*)take((size_t)2048 * 128 * 2);
    float* esum_d = (float*)take(128 * 4);
    float* esum_p = (float*)take(128 * 4);
    float* acc   = (float*)take(256);
    u32*   cnt   = (u32*)take(256);
    u16* X2 = epT;

    // -------- 1. prep (everything independent, one launch) --------
    {
        PREP p;
        p.e_p = e_p_adj; p.epT = epT;
        p.demb = demb; p.pemb = pemb;
        p.Wa1d = d_in[14]; p.ba1d = d_in[15];
        p.Wa1p = d_in[18]; p.ba1p = d_in[19];
        p.ko_d = ko_d; p.qs_d = qs_d; p.ko_p = ko_p; p.qs_p = qs_p;
        p.w1 = d_in[26]; p.w2 = d_in[28];
        p.wdg = d_in[8]; p.wd2 = d_in[22]; p.wpg = d_in[11]; p.wp3 = d_in[24];
        p.W1T = W1T; p.W2T = W2T; p.WcTe = WcTe; p.WcTp = WcTp;
        p.esum_d = esum_d; p.esum_p = esum_p;
        p.bdg_lin = d_in[9]; p.bdg = d_in[10]; p.bd2 = d_in[23];
        p.bpg_lin = d_in[12]; p.bpg = d_in[13]; p.bp3 = d_in[25];
        p.b_e = b_e; p.b_p = b_p;
        p.acc = acc; p.cnt = cnt;
        prep<<<5219, 256, 0, stream>>>(p);
    }

    // -------- 2. sparse fused attention + knn aggregation --------
    {
        SG s;
        s.demb = demb;
        s.adj[0] = e_p_adj; s.adjbf[0] = 0; s.qs[0] = qs_d; s.ko[0] = ko_d;
        s.w2[0] = d_in[16]; s.b2[0] = d_in[17]; s.embsum[0] = esum_p; s.emb[0] = pemb;
        s.outp[0] = A_e; s.coff[0] = 0; s.mode[0] = 0;
        s.adj[1] = e_e_adj; s.adjbf[1] = 0; s.qs[1] = nullptr; s.ko[1] = nullptr;
        s.w2[1] = nullptr; s.b2[1] = nullptr; s.embsum[1] = nullptr; s.emb[1] = demb;
        s.outp[1] = A_e; s.coff[1] = 128; s.mode[1] = 1;
        s.adj[2] = epT; s.adjbf[2] = 1; s.qs[2] = qs_p; s.ko[2] = ko_p;
        s.w2[2] = d_in[20]; s.b2[2] = d_in[21]; s.embsum[2] = esum_d; s.emb[2] = demb;
        s.outp[2] = A_p; s.coff[2] = 0; s.mode[2] = 0;
        s.adj[3] = p_p_adj; s.adjbf[3] = 0; s.qs[3] = nullptr; s.ko[3] = nullptr;
        s.w2[3] = nullptr; s.b2[3] = nullptr; s.embsum[3] = nullptr; s.emb[3] = pemb;
        s.outp[3] = A_p; s.coff[3] = 128; s.mode[3] = 1;
        sagg3<<<dim3(2048, 4), 512, 0, stream>>>(s);
    }

    auto setd = [&](GD2& g, int z, const u16* A, int lda, const u16* BT, int ldb,
                    u16* C, int ldc, int coff, int ki, const void* bi, int braw,
                    int act, int gath) {
        g.A[z] = A; g.lda[z] = lda; g.BT[z] = BT; g.ldb[z] = ldb;
        g.C[z] = C; g.ldc[z] = ldc; g.coff[z] = coff; g.kiters[z] = ki;
        g.bias[z] = bi; g.braw[z] = braw; g.act[z] = act; g.gather[z] = gath;
        g.he = h_e; g.hp = h_p; g.di = in_dis; g.dr = in_drug; g.demb = demb;
    };

    // -------- 3. combine GEMMs (both sides, one launch) --------
    {
        GD2 g;
        setd(g, 0, A_e, 256, WcTe, 256, h_e, 128, 0, 2, b_e, 0, 1, 0);
        setd(g, 1, A_p, 256, WcTp, 256, h_p, 128, 0, 2, b_p, 0, 1, 0);
        gemmF<<<dim3(128, 2), 256, 0, stream>>>(g);
    }

    // -------- 4. MLP1 with fused pair-gather --------
    {
        GD2 g;
        setd(g, 0, nullptr, 128, W1T, 128, X1, 128, 0, 1, d_in[27], 1, 1, 1);
        setd(g, 1, nullptr, 128, W1T, 128, X1, 128, 0, 1, d_in[27], 1, 1, 1);
        gemmF<<<dim3(1024, 1), 256, 0, stream>>>(g);
    }

    // -------- 5. MLP2 --------
    {
        GD2 g;
        setd(g, 0, X1, 128, W2T, 128, X2, 128, 0, 1, d_in[29], 1, 1, 0);
        setd(g, 1, X1, 128, W2T, 128, X2, 128, 0, 1, d_in[29], 1, 1, 0);
        gemmF<<<dim3(1024, 1), 256, 0, stream>>>(g);
    }

    // -------- 6. z / sigmoid / loss (self-finalizing) --------
    zloss2<<<64, 256, 0, stream>>>(X2, d_in[30], d_in[31], labels, out, acc, cnt, demb);
}

// Round 17
// 263.748 us; speedup vs baseline: 2.0499x; 2.0499x over previous
//
#include <hip/hip_runtime.h>

#define ND   2048
#define BB   16384

typedef unsigned short u16;
typedef unsigned int u32;
typedef unsigned long long u64;
typedef __attribute__((ext_vector_type(8))) short short8;
typedef __attribute__((ext_vector_type(4))) float f32x4;

__device__ inline float bf2f(u16 u) {
    union { u32 i; float f; } v; v.i = ((u32)u) << 16; return v.f;
}
__device__ inline u16 f2bf(float f) {
    union { float f; u32 i; } v; v.f = f;
    u32 i = v.i + 0x7fffu + ((v.i >> 16) & 1u);
    return (u16)(i >> 16);
}
__device__ inline float seluf(float x) {
    const float sc = 1.0507009873554805f, al = 1.6732632423543772f;
    return x > 0.f ? sc * x : sc * al * expm1f(x);
}

// ---- inline wave-level dtype sniffer: true => inputs are float32 ----------
__device__ inline bool detect_f32(const u16* demb) {
    int lane = threadIdx.x & 63;
    int sane = 0;
    #pragma unroll
    for (int i = 0; i < 2; i++) {
        u16 u = demb[lane * 4 + i * 2];   // even u16 idx = f32 low halves
        int e = (u >> 7) & 0xFF;
        if (u == 0 || (e >= 0x66 && e <= 0x8C)) sane++;
    }
    #pragma unroll
    for (int o = 32; o > 0; o >>= 1) sane += __shfl_down(sane, o, 64);
    return __shfl(sane, 0, 64) < 75;      // bf16 ~126/128 sane; f32 ~20/128
}
__device__ inline float rdv(const void* p, size_t i, bool f32) {
    return f32 ? ((const float*)p)[i] : bf2f(((const u16*)p)[i]);
}

// =================== PREP (one launch, flat grid ranges) ====================
// [0,4096)    : e_p -> epT bf16 transpose (32x32 tiles)
// [4096,5120) : koqs (8 rows x 1 mat per block)
// [5120,5216) : six 128x128 weight transposes (16 tiles each)
// [5216,5248) : embedding column-sum PARTIALS (16 blocks per side, ILP'd)
// [5248]      : combined biases + zero loss acc/counter
struct PREP {
    const void* e_p; u16* epT;
    const void* demb; const void* pemb;
    const void* Wa1d; const void* ba1d; const void* Wa1p; const void* ba1p;
    float* ko_d; float* qs_d; float* ko_p; float* qs_p;
    const void* w1; const void* w2; const void* wdg; const void* wd2;
    const void* wpg; const void* wp3;
    u16* W1T; u16* W2T; u16* WcTe; u16* WcTp;
    float* esumP;                       // [32][128]: 0..15 demb, 16..31 pemb
    const void* bdg_lin; const void* bdg; const void* bd2;
    const void* bpg_lin; const void* bpg; const void* bp3;
    u16* b_e; u16* b_p;
    float* acc; u32* cnt;
};

__global__ __launch_bounds__(256) void prep(PREP p) {
    bool f32 = detect_f32((const u16*)p.demb);
    int b = blockIdx.x;
    int tid = threadIdx.x;
    if (b < 4096) {                       // ---- epT transpose ----
        __shared__ u16 tile[32][33];
        int c0 = (b & 63) * 32, r0 = (b >> 6) * 32;
        int x = tid & 31, y = tid >> 5;   // y 0..7
        for (int i = y; i < 32; i += 8)
            tile[i][x] = f32 ? f2bf(((const float*)p.e_p)[(size_t)(r0 + i) * 2048 + c0 + x])
                             : ((const u16*)p.e_p)[(size_t)(r0 + i) * 2048 + c0 + x];
        __syncthreads();
        int rr = r0 + x;
        for (int i = y; i < 32; i += 8)
            p.epT[(size_t)(c0 + i) * 2048 + rr] = tile[x][i];
    } else if (b < 5120) {                // ---- koqs ----
        __shared__ float Wl[4096];
        __shared__ float xl[8][128];
        int kb = b - 4096;
        int mat = kb & 3, row0 = (kb >> 2) * 8;
        const void* emb; const void* W; size_t woff; const void* bias; float* out;
        switch (mat) {
            case 0:  emb = p.pemb; W = p.Wa1d; woff = 0;    bias = nullptr; out = p.ko_d; break;
            case 1:  emb = p.demb; W = p.Wa1d; woff = 4096; bias = p.ba1d;  out = p.qs_d; break;
            case 2:  emb = p.demb; W = p.Wa1p; woff = 0;    bias = nullptr; out = p.ko_p; break;
            default: emb = p.pemb; W = p.Wa1p; woff = 4096; bias = p.ba1p;  out = p.qs_p; break;
        }
        for (int i = tid; i < 4096; i += 256) Wl[i] = rdv(W, woff + i, f32);
        for (int i = tid; i < 1024; i += 256) {
            int r = i >> 7, k = i & 127;
            xl[r][k] = rdv(emb, (size_t)(row0 + r) * 128 + k, f32);
        }
        __syncthreads();
        int r = tid >> 5, a = tid & 31;
        float s = 0.f;
        #pragma unroll 8
        for (int k = 0; k < 128; k++) s += xl[r][k] * Wl[k * 32 + a];
        if (bias) s += rdv(bias, a, f32);
        out[(size_t)(row0 + r) * 32 + a] = s;
    } else if (b < 5216) {                // ---- small W transposes ----
        __shared__ u16 tile[32][33];
        int sb = b - 5120;
        int z = sb >> 4, t16 = sb & 15;
        int c0 = (t16 & 3) * 32, r0 = (t16 >> 2) * 32;
        const void* in; u16* out; int ldo, ooff;
        switch (z) {
            case 0:  in = p.w1;  out = p.W1T;  ldo = 128; ooff = 0;   break;
            case 1:  in = p.w2;  out = p.W2T;  ldo = 128; ooff = 0;   break;
            case 2:  in = p.wdg; out = p.WcTe; ldo = 256; ooff = 0;   break;
            case 3:  in = p.wd2; out = p.WcTe; ldo = 256; ooff = 128; break;
            case 4:  in = p.wpg; out = p.WcTp; ldo = 256; ooff = 0;   break;
            default: in = p.wp3; out = p.WcTp; ldo = 256; ooff = 128; break;
        }
        int x = tid & 31, y = tid >> 5;
        for (int i = y; i < 32; i += 8)
            tile[i][x] = f2bf(rdv(in, (size_t)(r0 + i) * 128 + c0 + x, f32));
        __syncthreads();
        int rr = r0 + x;
        for (int i = y; i < 32; i += 8)
            out[(size_t)(c0 + i) * ldo + ooff + rr] = tile[x][i];
    } else if (b < 5248) {                // ---- embsum partials (ILP'd) ----
        __shared__ float pt[2][128];
        int sb = b - 5216;                // 0..31
        int side = sb >> 4, part = sb & 15;
        const void* emb = side ? p.pemb : p.demb;
        int r0 = part * 128;
        int d = tid & 127, h = tid >> 7;
        float s0 = 0.f, s1 = 0.f, s2 = 0.f, s3 = 0.f;
        for (int r = h; r < 128; r += 8) {    // 4 independent loads in flight
            s0 += rdv(emb, (size_t)(r0 + r) * 128 + d, f32);
            s1 += rdv(emb, (size_t)(r0 + r + 2) * 128 + d, f32);
            s2 += rdv(emb, (size_t)(r0 + r + 4) * 128 + d, f32);
            s3 += rdv(emb, (size_t)(r0 + r + 6) * 128 + d, f32);
        }
        pt[h][d] = s0 + s1 + s2 + s3;
        __syncthreads();
        if (tid < 128)
            p.esumP[(size_t)(side * 16 + part) * 128 + tid] = pt[0][tid] + pt[1][tid];
    } else {                              // ---- biases + zero acc ----
        if (tid < 128) {
            p.b_e[tid] = f2bf(rdv(p.bdg_lin, tid, f32) + rdv(p.bdg, tid, f32) +
                              rdv(p.bd2, tid, f32));
            p.b_p[tid] = f2bf(rdv(p.bpg_lin, tid, f32) + rdv(p.bpg, tid, f32) +
                              rdv(p.bp3, tid, f32));
        }
        if (tid == 254) *p.acc = 0.f;
        if (tid == 255) *p.cnt = 0u;
    }
}

// =================== sparse fused aggregation v3 ===========================
// Phase 1: ballot-compact edges (no score). Phase 2: DENSE score compute over
// compacted list (full lane utilization). Then wave-0 wsum + accumulation.
// embsum[z] points at 16 partial vectors of 128 (summed in epilogue).
#define ECAP 512
struct SG {
    const void* adj[4]; int adjbf[4];
    const float* qs[4]; const float* ko[4];
    const void* w2[4]; const void* b2[4];
    const float* embsum[4];
    const void* emb[4];
    u16* outp[4]; int coff[4];
    int mode[4];
    const void* demb;
};

__global__ __launch_bounds__(512, 4) void sagg3(SG p) {
    __shared__ float accQ[4][128];
    __shared__ float qsh[32], w2sh[32];
    __shared__ float wlist[ECAP];
    __shared__ int jlist[ECAP];
    __shared__ int ecnt;
    __shared__ float wsum_sh;
    bool f32 = detect_f32((const u16*)p.demb);
    int z = blockIdx.y;
    int row = blockIdx.x;
    int tid = threadIdx.x;
    int lane = tid & 63;
    int mode = p.mode[z];
    bool f32a = (p.adjbf[z] == 0) && f32;
    if (tid < 128) { accQ[0][tid] = 0.f; accQ[1][tid] = 0.f;
                     accQ[2][tid] = 0.f; accQ[3][tid] = 0.f; }
    if (tid == 0) ecnt = 0;
    if (mode == 0) {
        if (tid < 32) qsh[tid] = p.qs[z][(size_t)row * 32 + tid];
        else if (tid < 64) w2sh[tid - 32] = (float)rdv(p.w2[z], tid - 32, f32);
    }
    __syncthreads();
    // phase 1: scan + compact (no score)
    float av[4];
    #pragma unroll
    for (int c = 0; c < 4; c++)
        av[c] = f32a ? ((const float*)p.adj[z])[(size_t)row * 2048 + c * 512 + tid]
                     : bf2f(((const u16*)p.adj[z])[(size_t)row * 2048 + c * 512 + tid]);
    u64 ltmask = ((u64)1 << lane) - 1;
    #pragma unroll
    for (int c = 0; c < 4; c++) {
        bool has = av[c] != 0.f;
        u64 mask = __ballot(has);
        int cnt = __popcll(mask);
        int base0 = 0;
        if (lane == 0 && cnt) base0 = atomicAdd(&ecnt, cnt);
        int base = __shfl(base0, 0, 64);
        int pos = base + (int)__popcll(mask & ltmask);
        if (has && pos < ECAP) { jlist[pos] = c * 512 + tid; wlist[pos] = av[c]; }
    }
    __syncthreads();
    int E = min(ecnt, ECAP);
    // phase 2: dense score compute over compacted edges (attention only)
    if (mode == 0) {
        float b2v = (float)rdv(p.b2[z], 0, f32);
        const float* ko = p.ko[z];
        for (int e = tid; e < E; e += 512) {
            int j = jlist[e];
            const float4* kp = (const float4*)(ko + (size_t)j * 32);
            float s = 0.f;
            #pragma unroll
            for (int qd = 0; qd < 8; qd++) {
                float4 kv = kp[qd];
                s += fmaxf(qsh[qd * 4 + 0] + kv.x, 0.f) * w2sh[qd * 4 + 0];
                s += fmaxf(qsh[qd * 4 + 1] + kv.y, 0.f) * w2sh[qd * 4 + 1];
                s += fmaxf(qsh[qd * 4 + 2] + kv.z, 0.f) * w2sh[qd * 4 + 2];
                s += fmaxf(qsh[qd * 4 + 3] + kv.w, 0.f) * w2sh[qd * 4 + 3];
            }
            s = fmaxf(s + b2v, 0.f);
            wlist[e] = expm1f(s);
        }
        __syncthreads();
    }
    // wave-0 weight-sum
    if (tid < 64) {
        float s = 0.f;
        for (int i = lane; i < E; i += 64) s += wlist[i];
        #pragma unroll
        for (int o = 32; o > 0; o >>= 1) s += __shfl_down(s, o, 64);
        if (lane == 0) wsum_sh = s;
    }
    // edge accumulation: 4-way edge parallel, 4-deep unroll
    int d = tid & 127, q = tid >> 7;
    const void* emb = p.emb[z];
    float acc = 0.f;
    int e = q;
    for (; e + 12 < E; e += 16) {
        float w0 = wlist[e],     w1 = wlist[e + 4];
        float w2 = wlist[e + 8], w3 = wlist[e + 12];
        int j0 = jlist[e],       j1 = jlist[e + 4];
        int j2 = jlist[e + 8],   j3 = jlist[e + 12];
        float v0 = rdv(emb, (size_t)j0 * 128 + d, f32);
        float v1 = rdv(emb, (size_t)j1 * 128 + d, f32);
        float v2 = rdv(emb, (size_t)j2 * 128 + d, f32);
        float v3 = rdv(emb, (size_t)j3 * 128 + d, f32);
        acc += w0 * v0 + w1 * v1 + w2 * v2 + w3 * v3;
    }
    for (; e < E; e += 4)
        acc += wlist[e] * rdv(emb, (size_t)jlist[e] * 128 + d, f32);
    accQ[q][d] = acc;
    __syncthreads();
    if (tid < 128) {
        float v = accQ[0][tid] + accQ[1][tid] + accQ[2][tid] + accQ[3][tid];
        float denom;
        if (mode == 0) {
            float es = 0.f;
            #pragma unroll
            for (int i = 0; i < 16; i++) es += p.embsum[z][(size_t)i * 128 + tid];
            v += es;
            denom = 2048.f + wsum_sh;
        } else denom = wsum_sh + 1e-8f;
        p.outp[z][(size_t)row * 256 + p.coff[z] + tid] = f2bf(v / denom);
    }
}

// =================== LDS-tiled MFMA GEMM (2-desc, optional gather-A) ========
struct GD2 {
    const u16* A[2]; const u16* BT[2]; u16* C[2];
    const void* bias[2]; int braw[2];
    int lda[2], ldb[2], ldc[2], coff[2], kiters[2], act[2], gather[2];
    const u16 *he, *hp; const int *di, *dr;
    const void* demb;
};

#define PADK 136

__global__ __launch_bounds__(256, 2) void gemmF(GD2 g) {
    __shared__ __align__(16) u16 As[16][PADK];
    __shared__ __align__(16) u16 Bs[128][PADK];
    bool f32 = detect_f32((const u16*)g.demb);
    int z = blockIdx.y;
    const u16* A = g.A[z];
    const u16* BT = g.BT[z];
    int lda = g.lda[z], ldb = g.ldb[z];
    int kiters = g.kiters[z];
    int gath = g.gather[z];
    int tid = threadIdx.x;
    int lane = tid & 63, wv = tid >> 6;
    int mrow = lane & 15, quad = lane >> 4;
    int m0 = blockIdx.x * 16;
    int c0 = wv * 32;
    int sr = tid >> 4, sk = (tid & 15) * 8;
    f32x4 acc0 = {0.f, 0.f, 0.f, 0.f}, acc1 = {0.f, 0.f, 0.f, 0.f};

    short8 ra, rb[8];
    auto ldstage = [&](int kb) {
        if (gath) {
            int r = m0 + sr;
            int ia = g.di[r], ic = g.dr[r];
            short8 he8 = *(const short8*)(g.he + (size_t)ia * 128 + sk);
            short8 hp8 = *(const short8*)(g.hp + (size_t)ic * 128 + sk);
            #pragma unroll
            for (int i = 0; i < 8; i++)
                ra[i] = (short)f2bf(bf2f((u16)he8[i]) * bf2f((u16)hp8[i]));
        } else {
            ra = *(const short8*)(A + (size_t)(m0 + sr) * lda + kb + sk);
        }
        const u16* bbase = BT + (size_t)sr * ldb + kb + sk;
        #pragma unroll
        for (int i = 0; i < 8; i++)
            rb[i] = *(const short8*)(bbase + (size_t)i * 16 * ldb);
    };
    auto ststage = [&]() {
        *(short8*)(&As[sr][sk]) = ra;
        #pragma unroll
        for (int i = 0; i < 8; i++)
            *(short8*)(&Bs[i * 16 + sr][sk]) = rb[i];
    };
    auto compute = [&]() {
        #pragma unroll
        for (int ks = 0; ks < 4; ks++) {
            short8 af = *(const short8*)(&As[mrow][ks * 32 + quad * 8]);
            short8 b0 = *(const short8*)(&Bs[c0 + mrow][ks * 32 + quad * 8]);
            short8 b1 = *(const short8*)(&Bs[c0 + 16 + mrow][ks * 32 + quad * 8]);
            acc0 = __builtin_amdgcn_mfma_f32_16x16x32_bf16(af, b0, acc0, 0, 0, 0);
            acc1 = __builtin_amdgcn_mfma_f32_16x16x32_bf16(af, b1, acc1, 0, 0, 0);
        }
    };

    ldstage(0);
    #pragma unroll 1
    for (int it = 0; it < kiters - 1; ++it) {
        ststage();
        __syncthreads();
        ldstage((it + 1) * 128);
        compute();
        __syncthreads();
    }
    ststage();
    __syncthreads();
    compute();

    const void* bi = g.bias[z];
    bool braw = g.braw[z] != 0;
    u16* C = g.C[z];
    int ldc = g.ldc[z], coff = g.coff[z], act = g.act[z];
    int n0 = c0 + mrow, n1 = n0 + 16;
    float bv0, bv1;
    if (braw) { bv0 = rdv(bi, n0, f32); bv1 = rdv(bi, n1, f32); }
    else      { bv0 = bf2f(((const u16*)bi)[n0]); bv1 = bf2f(((const u16*)bi)[n1]); }
    #pragma unroll
    for (int r = 0; r < 4; r++) {
        int rw = m0 + quad * 4 + r;
        float v0 = acc0[r] + bv0, v1 = acc1[r] + bv1;
        if (act) { v0 = seluf(v0); v1 = seluf(v1); }
        C[(size_t)rw * ldc + coff + n0] = f2bf(v0);
        C[(size_t)rw * ldc + coff + n1] = f2bf(v1);
    }
}

// =================== z / sigmoid / loss (self-finalizing) ===================
__global__ __launch_bounds__(256) void zloss2(
    const u16* __restrict__ X2, const void* __restrict__ wpred,
    const void* __restrict__ bpred, const int* __restrict__ labels,
    float* __restrict__ out, float* __restrict__ acc, u32* __restrict__ cnt,
    const void* __restrict__ demb) {
    __shared__ float wp[128];
    __shared__ float ls[256];
    bool f32 = detect_f32((const u16*)demb);
    int tid = threadIdx.x;
    if (tid < 128) wp[tid] = rdv(wpred, tid, f32);
    __syncthreads();
    int b = blockIdx.x * 256 + tid;
    const uint4* xp = (const uint4*)(X2 + (size_t)b * 128);
    float z = 0.f;
    #pragma unroll
    for (int i = 0; i < 16; i++) {
        uint4 q = xp[i];
        u32 u[4] = {q.x, q.y, q.z, q.w};
        #pragma unroll
        for (int c = 0; c < 4; c++) {
            z += bf2f((u16)(u[c] & 0xffff)) * wp[i * 8 + c * 2];
            z += bf2f((u16)(u[c] >> 16)) * wp[i * 8 + c * 2 + 1];
        }
    }
    z += rdv(bpred, 0, f32);
    out[1 + b] = 1.f / (1.f + __expf(-z));
    float y = (float)labels[b];
    ls[tid] = fmaxf(z, 0.f) - z * y + log1pf(__expf(-fabsf(z)));
    __syncthreads();
    for (int o = 128; o > 0; o >>= 1) {
        if (tid < o) ls[tid] += ls[tid + o];
        __syncthreads();
    }
    if (tid == 0) {
        atomicAdd(acc, ls[0]);
        __threadfence();
        u32 t = atomicAdd(cnt, 1u);
        if (t == 63) {
            __threadfence();
            out[0] = *(volatile float*)acc * (1.f / 16384.f);
        }
    }
}

// =================== launch (6 dispatches) ==================================
extern "C" void kernel_launch(void* const* d_in, const int* in_sizes, int n_in,
                              void* d_out, int out_size, void* d_ws, size_t ws_size,
                              hipStream_t stream) {
    const void* e_p_adj = d_in[0];
    const void* e_e_adj = d_in[1];
    const void* p_p_adj = d_in[2];
    const int* in_dis  = (const int*)d_in[3];
    const int* in_drug = (const int*)d_in[4];
    const int* labels  = (const int*)d_in[5];
    const void* demb = d_in[6];
    const void* pemb = d_in[7];
    float* out = (float*)d_out;

    // -------- workspace (~17 MB) --------
    char* ws = (char*)d_ws;
    size_t off = 0;
    auto take = [&](size_t bytes) { char* p = ws + off; off = (off + bytes + 255) & ~(size_t)255; return p; };
    u16*   epT   = (u16*)take((size_t)2048 * 2048 * 2);   // 8 MB; X2 aliases later
    u16*   X1    = (u16*)take((size_t)BB * 128 * 2);      // 4 MB
    float* ko_d  = (float*)take((size_t)2048 * 32 * 4);
    float* qs_d  = (float*)take((size_t)2048 * 32 * 4);
    float* ko_p  = (float*)take((size_t)2048 * 32 * 4);
    float* qs_p  = (float*)take((size_t)2048 * 32 * 4);
    u16*   A_e   = (u16*)take((size_t)2048 * 256 * 2);
    u16*   A_p   = (u16*)take((size_t)2048 * 256 * 2);
    u16*   WcTe  = (u16*)take((size_t)128 * 256 * 2);
    u16*   WcTp  = (u16*)take((size_t)128 * 256 * 2);
    u16*   W1T   = (u16*)take((size_t)128 * 128 * 2);
    u16*   W2T   = (u16*)take((size_t)128 * 128 * 2);
    u16*   b_e   = (u16*)take(256);
    u16*   b_p   = (u16*)take(256);
    u16*   h_e   = (u16*)take((size_t)2048 * 128 * 2);
    u16*   h_p   = (u16*)take((size_t)2048 * 128 * 2);
    float* esumP = (float*)take((size_t)32 * 128 * 4);    // partials
    float* acc   = (float*)take(256);
    u32*   cnt   = (u32*)take(256);
    u16* X2 = epT;

    // -------- 1. prep (everything independent, one launch) --------
    {
        PREP p;
        p.e_p = e_p_adj; p.epT = epT;
        p.demb = demb; p.pemb = pemb;
        p.Wa1d = d_in[14]; p.ba1d = d_in[15];
        p.Wa1p = d_in[18]; p.ba1p = d_in[19];
        p.ko_d = ko_d; p.qs_d = qs_d; p.ko_p = ko_p; p.qs_p = qs_p;
        p.w1 = d_in[26]; p.w2 = d_in[28];
        p.wdg = d_in[8]; p.wd2 = d_in[22]; p.wpg = d_in[11]; p.wp3 = d_in[24];
        p.W1T = W1T; p.W2T = W2T; p.WcTe = WcTe; p.WcTp = WcTp;
        p.esumP = esumP;
        p.bdg_lin = d_in[9]; p.bdg = d_in[10]; p.bd2 = d_in[23];
        p.bpg_lin = d_in[12]; p.bpg = d_in[13]; p.bp3 = d_in[25];
        p.b_e = b_e; p.b_p = b_p;
        p.acc = acc; p.cnt = cnt;
        prep<<<5249, 256, 0, stream>>>(p);
    }

    // -------- 2. sparse fused attention + knn aggregation --------
    {
        SG s;
        s.demb = demb;
        s.adj[0] = e_p_adj; s.adjbf[0] = 0; s.qs[0] = qs_d; s.ko[0] = ko_d;
        s.w2[0] = d_in[16]; s.b2[0] = d_in[17];
        s.embsum[0] = esumP + 16 * 128; s.emb[0] = pemb;
        s.outp[0] = A_e; s.coff[0] = 0; s.mode[0] = 0;
        s.adj[1] = e_e_adj; s.adjbf[1] = 0; s.qs[1] = nullptr; s.ko[1] = nullptr;
        s.w2[1] = nullptr; s.b2[1] = nullptr; s.embsum[1] = nullptr; s.emb[1] = demb;
        s.outp[1] = A_e; s.coff[1] = 128; s.mode[1] = 1;
        s.adj[2] = epT; s.adjbf[2] = 1; s.qs[2] = qs_p; s.ko[2] = ko_p;
        s.w2[2] = d_in[20]; s.b2[2] = d_in[21];
        s.embsum[2] = esumP; s.emb[2] = demb;
        s.outp[2] = A_p; s.coff[2] = 0; s.mode[2] = 0;
        s.adj[3] = p_p_adj; s.adjbf[3] = 0; s.qs[3] = nullptr; s.ko[3] = nullptr;
        s.w2[3] = nullptr; s.b2[3] = nullptr; s.embsum[3] = nullptr; s.emb[3] = pemb;
        s.outp[3] = A_p; s.coff[3] = 128; s.mode[3] = 1;
        sagg3<<<dim3(2048, 4), 512, 0, stream>>>(s);
    }

    auto setd = [&](GD2& g, int z, const u16* A, int lda, const u16* BT, int ldb,
                    u16* C, int ldc, int coff, int ki, const void* bi, int braw,
                    int act, int gath) {
        g.A[z] = A; g.lda[z] = lda; g.BT[z] = BT; g.ldb[z] = ldb;
        g.C[z] = C; g.ldc[z] = ldc; g.coff[z] = coff; g.kiters[z] = ki;
        g.bias[z] = bi; g.braw[z] = braw; g.act[z] = act; g.gather[z] = gath;
        g.he = h_e; g.hp = h_p; g.di = in_dis; g.dr = in_drug; g.demb = demb;
    };

    // -------- 3. combine GEMMs (both sides, one launch) --------
    {
        GD2 g;
        setd(g, 0, A_e, 256, WcTe, 256, h_e, 128, 0, 2, b_e, 0, 1, 0);
        setd(g, 1, A_p, 256, WcTp, 256, h_p, 128, 0, 2, b_p, 0, 1, 0);
        gemmF<<<dim3(128, 2), 256, 0, stream>>>(g);
    }

    // -------- 4. MLP1 with fused pair-gather --------
    {
        GD2 g;
        setd(g, 0, nullptr, 128, W1T, 128, X1, 128, 0, 1, d_in[27], 1, 1, 1);
        setd(g, 1, nullptr, 128, W1T, 128, X1, 128, 0, 1, d_in[27], 1, 1, 1);
        gemmF<<<dim3(1024, 1), 256, 0, stream>>>(g);
    }

    // -------- 5. MLP2 --------
    {
        GD2 g;
        setd(g, 0, X1, 128, W2T, 128, X2, 128, 0, 1, d_in[29], 1, 1, 0);
        setd(g, 1, X1, 128, W2T, 128, X2, 128, 0, 1, d_in[29], 1, 1, 0);
        gemmF<<<dim3(1024, 1), 256, 0, stream>>>(g);
    }

    // -------- 6. z / sigmoid / loss (self-finalizing) --------
    zloss2<<<64, 256, 0, stream>>>(X2, d_in[30], d_in[31], labels, out, acc, cnt, demb);
}